// Round 1
// baseline (1238.245 us; speedup 1.0000x reference)
//
#include <hip/hip_runtime.h>

#define B_ 64
#define T_ 2048
#define IN_ 64
#define H_ 128
#define C_ 8

// ---------------- helpers ----------------
__device__ __forceinline__ float tanh_fast(float x) {
  float e = __expf(2.0f * x);                       // v_exp_f32 path
  return 1.0f - 2.0f * __builtin_amdgcn_rcpf(e + 1.0f);
}

__device__ __forceinline__ void fma4(float4& a, const float4 w, const float4 h) {
  a.x = fmaf(w.x, h.x, a.x);
  a.y = fmaf(w.y, h.y, a.y);
  a.z = fmaf(w.z, h.z, a.z);
  a.w = fmaf(w.w, h.w, a.w);
}
__device__ __forceinline__ float hsum4(const float4 a) { return (a.x + a.y) + (a.z + a.w); }

// butterfly adds: xor1/xor2 on the VALU via DPP quad_perm (no LDS traffic)
__device__ __forceinline__ float dpp_add_x1(float v) {
  return v + __int_as_float(__builtin_amdgcn_update_dpp(0, __float_as_int(v), 0xB1, 0xF, 0xF, true));
}
__device__ __forceinline__ float dpp_add_x2(float v) {
  return v + __int_as_float(__builtin_amdgcn_update_dpp(0, __float_as_int(v), 0x4E, 0xF, 0xF, true));
}
// xor4 via ds_swizzle (stays within 32-lane half)
__device__ __forceinline__ float swz_add_x4(float v) {
  return v + __int_as_float(__builtin_amdgcn_ds_swizzle(__float_as_int(v), 0x101F));
}

// barrier WITHOUT the vmcnt(0) drain __syncthreads would emit:
// keeps global prefetch loads in flight across steps; LDS ordering via lgkmcnt(0).
__device__ __forceinline__ void block_sync_lds() {
  asm volatile("s_waitcnt lgkmcnt(0)" ::: "memory");
  __builtin_amdgcn_s_barrier();
  asm volatile("" ::: "memory");
}

// ---------------- kernel 1: xp0 = x @ W_ih0^T + b_ih0 + b_hh0 ----------------
// one wave per group of rows; W rows held in VGPRs (lane holds rows lane, lane+64)
__global__ __launch_bounds__(256) void k_xproj0(
    const float* __restrict__ x,
    const float* __restrict__ Wih0,
    const float* __restrict__ bih0,
    const float* __restrict__ bhh0,
    float* __restrict__ xp0) {
  __shared__ __align__(16) float xs[4][IN_];
  const int wave = threadIdx.x >> 6;
  const int lane = threadIdx.x & 63;
  const int gw   = blockIdx.x * 4 + wave;        // 0..2047
  const int rows = (B_ * T_) / 2048;             // 64
  const int r0   = gw * rows;

  float4 w0[16], w1[16];
  const float4* W4 = (const float4*)Wih0;        // row stride 16 float4
#pragma unroll
  for (int k = 0; k < 16; ++k) {
    w0[k] = W4[lane * 16 + k];
    w1[k] = W4[(lane + 64) * 16 + k];
  }
  const float ba = bih0[lane] + bhh0[lane];
  const float bb = bih0[lane + 64] + bhh0[lane + 64];

  float xnext = x[(size_t)r0 * IN_ + lane];      // prefetch row 0
  for (int rr = 0; rr < rows; ++rr) {
    const int r = r0 + rr;
    xs[wave][lane] = xnext;
    if (rr + 1 < rows) xnext = x[(size_t)(r + 1) * IN_ + lane];  // prefetch next row
    asm volatile("s_waitcnt lgkmcnt(0)" ::: "memory");           // ds_write visible (same wave)
    float4 a0 = {0.f, 0.f, 0.f, 0.f}, a1 = {0.f, 0.f, 0.f, 0.f};
    const float4* xv = (const float4*)xs[wave];
#pragma unroll
    for (int k = 0; k < 16; ++k) {
      float4 h = xv[k];
      fma4(a0, w0[k], h);
      fma4(a1, w1[k], h);
    }
    xp0[(size_t)r * H_ + lane]      = hsum4(a0) + ba;
    xp0[(size_t)r * H_ + 64 + lane] = hsum4(a1) + bb;
  }
}

// ---------------- kernel 2: fused 2-layer recurrence + FC head ----------------
// one block per batch. 13 waves:
//   waves 0-3 : layer0   h1[s]   = tanh(xp0[s] + Whh0 @ h1[s-1])
//   waves 4-11: layer1   h2[s-1] = tanh(b + Wih1 @ h1[s-1] + Whh1 @ h2[s-2])
//   wave 12   : FC       logits[s-2] = Wfc @ h2[s-2] + bfc
// depth-2 LDS rings; one barrier per step; weights in VGPRs.
#define L0STEP(SS, XA, XB)                                               \
  {                                                                      \
    block_sync_lds();                                                    \
    const int s_ = (SS);                                                 \
    if (s_ < T_) {                                                       \
      const float4* hp = (const float4*)h1r[(s_ + 1) & 1];               \
      float4 a0 = {0.f,0.f,0.f,0.f}, a1 = {0.f,0.f,0.f,0.f};             \
      _Pragma("unroll")                                                  \
      for (int k4 = 0; k4 < 8; ++k4) {                                   \
        float4 hv = hp[kq * 8 + ((k4 + 2 * kq) & 7)];                    \
        fma4(a0, wa[k4], hv);                                            \
        fma4(a1, wb[k4], hv);                                            \
      }                                                                  \
      float t0 = dpp_add_x2(dpp_add_x1(hsum4(a0)));                      \
      float t1 = dpp_add_x2(dpp_add_x1(hsum4(a1)));                      \
      if (kq == 0) {                                                     \
        h1r[s_ & 1][j]      = tanh_fast(t0 + XA);                        \
        h1r[s_ & 1][j + 64] = tanh_fast(t1 + XB);                        \
        const int sp = s_ + 4;                                           \
        if (sp < T_) {                                                   \
          XA = xp0[xpb + (size_t)sp * H_ + j];                           \
          XB = xp0[xpb + (size_t)sp * H_ + j + 64];                      \
        }                                                                \
      }                                                                  \
    }                                                                    \
  }

__global__ __launch_bounds__(832) void k_rnn(
    const float* __restrict__ xp0,
    const float* __restrict__ Whh0,
    const float* __restrict__ Wih1,
    const float* __restrict__ Whh1,
    const float* __restrict__ bih1,
    const float* __restrict__ bhh1,
    const float* __restrict__ Wfc,
    const float* __restrict__ bfc,
    float* __restrict__ out) {
  __shared__ __align__(16) float h1r[2][H_];
  __shared__ __align__(16) float h2r[2][H_];

  const int tid  = threadIdx.x;
  const int wave = tid >> 6;
  const int lane = tid & 63;
  const int b    = blockIdx.x;

  if (tid < 2 * H_) {                 // zero both ring slots (h0 = 0)
    ((float*)h1r)[tid] = 0.f;
    ((float*)h2r)[tid] = 0.f;
  }
  block_sync_lds();

  if (wave < 4) {
    // ---------------- layer 0 ----------------
    const int jj = lane >> 2;          // 0..15
    const int kq = lane & 3;           // k-quarter of 128
    const int j  = wave * 16 + jj;     // outputs j, j+64
    const float4* W4 = (const float4*)Whh0;   // row stride 32 float4
    float4 wa[8], wb[8];
#pragma unroll
    for (int k4 = 0; k4 < 8; ++k4) {   // pre-rotated chunks (bank-conflict-free reads)
      const int m = (k4 + 2 * kq) & 7;
      wa[k4] = W4[j * 32 + kq * 8 + m];
      wb[k4] = W4[(j + 64) * 32 + kq * 8 + m];
    }
    const size_t xpb = (size_t)b * T_ * H_;
    float XA0 = 0.f, XA1 = 0.f, XA2 = 0.f, XA3 = 0.f;
    float XB0 = 0.f, XB1 = 0.f, XB2 = 0.f, XB3 = 0.f;
    if (kq == 0) {                     // distance-4 prefetch prologue
      XA0 = xp0[xpb + 0 * H_ + j]; XB0 = xp0[xpb + 0 * H_ + j + 64];
      XA1 = xp0[xpb + 1 * H_ + j]; XB1 = xp0[xpb + 1 * H_ + j + 64];
      XA2 = xp0[xpb + 2 * H_ + j]; XB2 = xp0[xpb + 2 * H_ + j + 64];
      XA3 = xp0[xpb + 3 * H_ + j]; XB3 = xp0[xpb + 3 * H_ + j + 64];
    }
    for (int s0 = 0; s0 < T_ + 4; s0 += 4) {   // 2052 steps total
      L0STEP(s0 + 0, XA0, XB0);
      L0STEP(s0 + 1, XA1, XB1);
      L0STEP(s0 + 2, XA2, XB2);
      L0STEP(s0 + 3, XA3, XB3);
    }
  } else if (wave < 12) {
    // ---------------- layer 1 ----------------
    const int w1 = wave - 4;           // 0..7
    const int jj = lane >> 3;          // 0..7
    const int ke = lane & 7;           // 8-way split over [Wih1 | Whh1]
    const int j  = w1 * 8 + jj;        // outputs j, j+64
    const int kq = ke & 3;
    const float4* W4 = (const float4*)((ke < 4) ? Wih1 : Whh1);
    float4 va[8], vb[8];
#pragma unroll
    for (int k4 = 0; k4 < 8; ++k4) {
      const int m = (k4 + ke) & 7;
      va[k4] = W4[j * 32 + kq * 8 + m];
      vb[k4] = W4[(j + 64) * 32 + kq * 8 + m];
    }
    const float bA = bih1[j] + bhh1[j];
    const float bB = bih1[j + 64] + bhh1[j + 64];
    for (int s = 0; s < T_ + 4; ++s) {
      block_sync_lds();
      if (s >= 1 && s <= T_) {
        const float* hbase = (ke < 4) ? h1r[(s + 1) & 1]   // h1[s-1]
                                      : h2r[s & 1];        // h2[s-2]
        const float4* hp = (const float4*)hbase;
        float4 a0 = {0.f,0.f,0.f,0.f}, a1 = {0.f,0.f,0.f,0.f};
#pragma unroll
        for (int k4 = 0; k4 < 8; ++k4) {
          float4 hv = hp[kq * 8 + ((k4 + ke) & 7)];
          fma4(a0, va[k4], hv);
          fma4(a1, vb[k4], hv);
        }
        float t0 = swz_add_x4(dpp_add_x2(dpp_add_x1(hsum4(a0))));
        float t1 = swz_add_x4(dpp_add_x2(dpp_add_x1(hsum4(a1))));
        if (ke == 0) {
          h2r[(s + 1) & 1][j]      = tanh_fast(t0 + bA);   // slot (s-1)&1
          h2r[(s + 1) & 1][j + 64] = tanh_fast(t1 + bB);
        }
      }
    }
  } else {
    // ---------------- FC head ----------------
    const int c   = lane >> 3;         // 0..7
    const int seg = lane & 7;          // 16-float segment
    const float4* W4 = (const float4*)Wfc;    // row stride 32 float4
    float4 wf[4];
#pragma unroll
    for (int k4 = 0; k4 < 4; ++k4) wf[k4] = W4[c * 32 + seg * 4 + k4];
    const float bv = bfc[c];
    float* outb = out + (size_t)b * T_ * C_;
    for (int s = 0; s < T_ + 4; ++s) {
      block_sync_lds();
      if (s >= 2 && s < T_ + 2) {
        const float4* hp = (const float4*)h2r[s & 1];      // h2[s-2]
        float4 a = {0.f,0.f,0.f,0.f};
#pragma unroll
        for (int k4 = 0; k4 < 4; ++k4) fma4(a, wf[k4], hp[seg * 4 + k4]);
        float t = swz_add_x4(dpp_add_x2(dpp_add_x1(hsum4(a))));
        if (seg == 0) outb[(size_t)(s - 2) * C_ + c] = t + bv;
      }
    }
  }
}

// ---------------- launch ----------------
extern "C" void kernel_launch(void* const* d_in, const int* in_sizes, int n_in,
                              void* d_out, int out_size, void* d_ws, size_t ws_size,
                              hipStream_t stream) {
  const float* x    = (const float*)d_in[0];
  const float* Wih0 = (const float*)d_in[1];
  const float* Whh0 = (const float*)d_in[2];
  const float* bih0 = (const float*)d_in[3];
  const float* bhh0 = (const float*)d_in[4];
  const float* Wih1 = (const float*)d_in[5];
  const float* Whh1 = (const float*)d_in[6];
  const float* bih1 = (const float*)d_in[7];
  const float* bhh1 = (const float*)d_in[8];
  const float* Wfc  = (const float*)d_in[9];
  const float* bfc  = (const float*)d_in[10];
  float* outp = (float*)d_out;
  float* xp0  = (float*)d_ws;   // B*T*H fp32 = 64 MiB scratch

  k_xproj0<<<512, 256, 0, stream>>>(x, Wih0, bih0, bhh0, xp0);
  k_rnn<<<64, 832, 0, stream>>>(xp0, Whh0, Wih1, Whh1, bih1, bhh1, Wfc, bfc, outp);
}

// Round 2
// 1103.512 us; speedup vs baseline: 1.1221x; 1.1221x over previous
//
#include <hip/hip_runtime.h>

#define B_ 64
#define T_ 2048
#define IN_ 64
#define H_ 128
#define C_ 8

typedef _Float16 f16x2 __attribute__((ext_vector_type(2)));

__device__ __forceinline__ f16x2 pk(float a, float b) {
  f16x2 r; r.x = (_Float16)a; r.y = (_Float16)b; return r;   // RNE converts
}
__device__ __forceinline__ f16x2 as_h2(int v) { return __builtin_bit_cast(f16x2, v); }

__device__ __forceinline__ float dot2(f16x2 a, f16x2 b, float c) {
#if __has_builtin(__builtin_amdgcn_fdot2)
  return __builtin_amdgcn_fdot2(a, b, c, false);
#else
  float r;
  asm("v_dot2_f32_f16 %0, %1, %2, %3" : "=v"(r) : "v"(a), "v"(b), "v"(c));
  return r;
#endif
}

__device__ __forceinline__ float tanh_fast(float x) {
  float e = __expf(2.0f * x);
  return 1.0f - 2.0f * __builtin_amdgcn_rcpf(e + 1.0f);
}

__device__ __forceinline__ float dpp_add_x1(float v) {
  return v + __int_as_float(__builtin_amdgcn_update_dpp(0, __float_as_int(v), 0xB1, 0xF, 0xF, true));
}
__device__ __forceinline__ float dpp_add_x2(float v) {
  return v + __int_as_float(__builtin_amdgcn_update_dpp(0, __float_as_int(v), 0x4E, 0xF, 0xF, true));
}
__device__ __forceinline__ float swz_add_x4(float v) {
  return v + __int_as_float(__builtin_amdgcn_ds_swizzle(__float_as_int(v), 0x101F));
}

// barrier without the vmcnt(0) drain of __syncthreads (keeps global prefetch in flight)
__device__ __forceinline__ void block_sync_lds() {
  asm volatile("s_waitcnt lgkmcnt(0)" ::: "memory");
  __builtin_amdgcn_s_barrier();
  asm volatile("" ::: "memory");
}

#define DOT8(A, Q, W, BASE)            \
  A = dot2(as_h2(Q.x), W[BASE+0], A);  \
  A = dot2(as_h2(Q.y), W[BASE+1], A);  \
  A = dot2(as_h2(Q.z), W[BASE+2], A);  \
  A = dot2(as_h2(Q.w), W[BASE+3], A);

// ---------------- kernel 1: xp0 = f16(x @ W_ih0^T + b_ih0 + b_hh0) ----------------
__global__ __launch_bounds__(256) void k_xproj(
    const float* __restrict__ x, const float* __restrict__ Wih0,
    const float* __restrict__ bih0, const float* __restrict__ bhh0,
    _Float16* __restrict__ xp) {
  __shared__ __align__(16) _Float16 xs[4][2][IN_];
  const int wave = threadIdx.x >> 6, lane = threadIdx.x & 63;
  const int gw = blockIdx.x * 4 + wave;          // 0..4095
  const int ROWS = 32;                           // 4096 waves * 32 = 131072 rows
  const size_t r0 = (size_t)gw * ROWS;

  f16x2 wA[32], wB[32];                          // rows lane*2, lane*2+1 of Wih0 (64 cols)
  const float2* W2 = (const float2*)Wih0;
#pragma unroll
  for (int p = 0; p < 32; ++p) {
    float2 a = W2[(lane * 2) * 32 + p];
    float2 b = W2[(lane * 2 + 1) * 32 + p];
    wA[p] = pk(a.x, a.y); wB[p] = pk(b.x, b.y);
  }
  const float ba = bih0[lane * 2] + bhh0[lane * 2];
  const float bb = bih0[lane * 2 + 1] + bhh0[lane * 2 + 1];

  xs[wave][0][lane] = (_Float16)x[r0 * IN_ + lane];   // row 0
  float xn = x[(r0 + 1) * IN_ + lane];                // prefetch row 1
  for (int rr = 0; rr < ROWS; ++rr) {
    const int buf = rr & 1;
    if (rr + 1 < ROWS) xs[wave][buf ^ 1][lane] = (_Float16)xn;   // write row rr+1
    if (rr + 2 < ROWS) xn = x[(r0 + rr + 2) * IN_ + lane];       // load row rr+2
    asm volatile("s_waitcnt lgkmcnt(0)" ::: "memory");
    const int4* xv = (const int4*)xs[wave][buf];
    int4 q0 = xv[0], q1 = xv[1], q2 = xv[2], q3 = xv[3];
    int4 q4 = xv[4], q5 = xv[5], q6 = xv[6], q7 = xv[7];
    float a0 = 0.f, a1 = 0.f, c0 = 0.f, c1 = 0.f;
    DOT8(a0, q0, wA, 0)  DOT8(c0, q0, wB, 0)
    DOT8(a1, q1, wA, 4)  DOT8(c1, q1, wB, 4)
    DOT8(a0, q2, wA, 8)  DOT8(c0, q2, wB, 8)
    DOT8(a1, q3, wA, 12) DOT8(c1, q3, wB, 12)
    DOT8(a0, q4, wA, 16) DOT8(c0, q4, wB, 16)
    DOT8(a1, q5, wA, 20) DOT8(c1, q5, wB, 20)
    DOT8(a0, q6, wA, 24) DOT8(c0, q6, wB, 24)
    DOT8(a1, q7, wA, 28) DOT8(c1, q7, wB, 28)
    *(f16x2*)&xp[(r0 + rr) * H_ + lane * 2] = pk(a0 + a1 + ba, c0 + c1 + bb);
  }
}

// ---------------- kernel 2: fused recurrence (f16 state/weights, dot2) ----------------
// LDS layout hlds[4][128] f16: [0]=h1 slot0 [1]=h1 slot1 [2]=h2 slot0 [3]=h2 slot1
// step s: L0 writes h1[s] -> slot s&1; L1 reads h1[s-1] (slot (s+1)&1) + h2[s-2]
// (slot s&1), writes h2[s-1] -> slot (s+1)&1; FC reads h2[s-2] (slot s&1).
#define L0STEP(SS, XA, RI, WI)                                             \
  {                                                                        \
    block_sync_lds();                                                      \
    const int s_ = (SS);                                                   \
    if (s_ < T_) {                                                         \
      int4 q0 = hp[(RI) + rot0], q1 = hp[(RI) + rot1];                     \
      int4 q2 = hp[(RI) + rot2], q3 = hp[(RI) + rot3];                     \
      float a0 = 0.f, a1 = 0.f, c0 = 0.f, c1 = 0.f;                        \
      DOT8(a0, q0, wA, 0)  DOT8(c0, q0, wB, 0)                             \
      DOT8(a1, q1, wA, 4)  DOT8(c1, q1, wB, 4)                             \
      DOT8(a0, q2, wA, 8)  DOT8(c0, q2, wB, 8)                             \
      DOT8(a1, q3, wA, 12) DOT8(c1, q3, wB, 12)                            \
      float ra = dpp_add_x2(dpp_add_x1(a0 + a1));                          \
      float rc = dpp_add_x2(dpp_add_x1(c0 + c1));                          \
      float t0 = tanh_fast(ra + (float)XA.x);                              \
      float t1 = tanh_fast(rc + (float)XA.y);                              \
      const int sp = s_ + 4;                                               \
      if (sp < T_) XA = xp2[xpb + (size_t)sp * 64 + jx];                   \
      if (kq == 0) wp[(WI)] = pk(t0, t1);                                  \
    }                                                                      \
  }

#define L1STEP(SS, RI, WI)                                                 \
  {                                                                        \
    block_sync_lds();                                                      \
    const int s_ = (SS);                                                   \
    if (s_ >= 1 && s_ <= T_) {                                             \
      int4 q0 = hp[(RI) + rot0], q1 = hp[(RI) + rot1];                     \
      int4 q2 = hp[(RI) + rot2], q3 = hp[(RI) + rot3];                     \
      float a0 = 0.f, a1 = 0.f, c0 = 0.f, c1 = 0.f;                        \
      DOT8(a0, q0, vA, 0)  DOT8(c0, q0, vB, 0)                             \
      DOT8(a1, q1, vA, 4)  DOT8(c1, q1, vB, 4)                             \
      DOT8(a0, q2, vA, 8)  DOT8(c0, q2, vB, 8)                             \
      DOT8(a1, q3, vA, 12) DOT8(c1, q3, vB, 12)                            \
      float ra = swz_add_x4(dpp_add_x2(dpp_add_x1(a0 + a1)));              \
      float rc = swz_add_x4(dpp_add_x2(dpp_add_x1(c0 + c1)));              \
      float t0 = tanh_fast(ra + bA);                                       \
      float t1 = tanh_fast(rc + bB);                                       \
      if (ke == 0) wp[(WI)] = pk(t0, t1);                                  \
    }                                                                      \
  }

#define FCSTEP(SS, RI)                                                     \
  {                                                                        \
    block_sync_lds();                                                      \
    const int s_ = (SS);                                                   \
    if (s_ >= 2 && s_ < T_ + 2) {                                          \
      int4 q0 = hp[(RI)], q1 = hp[(RI) + 1];                               \
      float a0 = 0.f, a1 = 0.f;                                            \
      DOT8(a0, q0, wf, 0) DOT8(a1, q1, wf, 4)                              \
      float r = swz_add_x4(dpp_add_x2(dpp_add_x1(a0 + a1)));               \
      if (k8 == 0) outb[(size_t)(s_ - 2) * C_ + c] = r + bv;               \
    }                                                                      \
  }

__global__ __launch_bounds__(832) void k_rnn(
    const _Float16* __restrict__ xp0,
    const float* __restrict__ Whh0,
    const float* __restrict__ Wih1,
    const float* __restrict__ Whh1,
    const float* __restrict__ bih1,
    const float* __restrict__ bhh1,
    const float* __restrict__ Wfc,
    const float* __restrict__ bfc,
    float* __restrict__ out) {
  __shared__ __align__(16) _Float16 hlds[4][H_];

  const int tid  = threadIdx.x;
  const int wave = tid >> 6;
  const int lane = tid & 63;
  const int b    = blockIdx.x;

  if (tid < 256) ((int*)hlds)[tid] = 0;          // zero all slots (h0 = 0)
  const int4*  hp = (const int4*)hlds;
  f16x2*       wp = (f16x2*)hlds;
  block_sync_lds();

  if (wave < 4) {
    // ---------------- layer 0: 4 waves, outputs j0 = w*32+jj*2 (+1), kq k-quarter
    const int jj = lane >> 2, kq = lane & 3;
    const int j0 = wave * 32 + jj * 2;
    const int rot0 = kq, rot1 = (1 + kq) & 3, rot2 = (2 + kq) & 3, rot3 = (3 + kq) & 3;
    f16x2 wA[16], wB[16];
    const float2* W2 = (const float2*)Whh0;      // row stride 64 float2
#pragma unroll
    for (int m = 0; m < 4; ++m) {
      const int cb = kq * 16 + (((m + kq) & 3)) * 4;   // float2 units
#pragma unroll
      for (int p = 0; p < 4; ++p) {
        float2 a = W2[j0 * 64 + cb + p];
        float2 bt = W2[(j0 + 1) * 64 + cb + p];
        wA[m * 4 + p] = pk(a.x, a.y);
        wB[m * 4 + p] = pk(bt.x, bt.y);
      }
    }
    const int riE = 16 + kq * 4, riO = kq * 4;   // read slot (s+1)&1, int4 units
    const int wiE = (j0 >> 1), wiO = 64 + (j0 >> 1);
    const size_t xpb = (size_t)b * T_ * 64;      // f16x2 units
    const int jx = wave * 16 + jj;
    const f16x2* xp2 = (const f16x2*)xp0;
    f16x2 XA0 = xp2[xpb + 0 * 64 + jx], XA1 = xp2[xpb + 1 * 64 + jx];
    f16x2 XA2 = xp2[xpb + 2 * 64 + jx], XA3 = xp2[xpb + 3 * 64 + jx];
    for (int s0 = 0; s0 < T_ + 4; s0 += 4) {
      L0STEP(s0 + 0, XA0, riE, wiE)
      L0STEP(s0 + 1, XA1, riO, wiO)
      L0STEP(s0 + 2, XA2, riE, wiE)
      L0STEP(s0 + 3, XA3, riO, wiO)
    }
  } else if (wave < 12) {
    // ---------------- layer 1: 8 waves, outputs j0 = u*16+jj*2 (+1)
    const int u = wave - 4;
    const int jj = lane >> 3, ke = lane & 7, kq = ke & 3;
    const int j0 = u * 16 + jj * 2;
    const int rot0 = kq, rot1 = (1 + kq) & 3, rot2 = (2 + kq) & 3, rot3 = (3 + kq) & 3;
    f16x2 vA[16], vB[16];
    const float2* W2 = (const float2*)(ke < 4 ? Wih1 : Whh1);
#pragma unroll
    for (int m = 0; m < 4; ++m) {
      const int cb = kq * 16 + (((m + kq) & 3)) * 4;
#pragma unroll
      for (int p = 0; p < 4; ++p) {
        float2 a = W2[j0 * 64 + cb + p];
        float2 bt = W2[(j0 + 1) * 64 + cb + p];
        vA[m * 4 + p] = pk(a.x, a.y);
        vB[m * 4 + p] = pk(bt.x, bt.y);
      }
    }
    const float bA = bih1[j0] + bhh1[j0];
    const float bB = bih1[j0 + 1] + bhh1[j0 + 1];
    // read base: ih -> h1 slot (s+1)&1 ; hh -> h2 slot s&1   (int4 units)
    const int riE = (ke < 4 ? 16 : 32) + kq * 4;
    const int riO = (ke < 4 ? 0 : 48) + kq * 4;
    const int wiE = 192 + (j0 >> 1), wiO = 128 + (j0 >> 1);  // h2 slot (s+1)&1
    for (int s = 0; s < T_ + 4; s += 2) {
      L1STEP(s,     riE, wiE)
      L1STEP(s + 1, riO, wiO)
    }
  } else {
    // ---------------- FC head: 1 wave, class c, k8 16-elem segment
    const int c = lane >> 3, k8 = lane & 7;
    f16x2 wf[8];
    const float2* W2 = (const float2*)Wfc;       // row stride 64 float2
#pragma unroll
    for (int p = 0; p < 8; ++p) {
      float2 a = W2[c * 64 + k8 * 8 + p];
      wf[p] = pk(a.x, a.y);
    }
    const float bv = bfc[c];
    float* outb = out + (size_t)b * T_ * C_;
    const int riE = 32 + k8 * 2, riO = 48 + k8 * 2;   // h2 slot s&1
    for (int s = 0; s < T_ + 4; s += 2) {
      FCSTEP(s,     riE)
      FCSTEP(s + 1, riO)
    }
  }
}

// ---------------- launch ----------------
extern "C" void kernel_launch(void* const* d_in, const int* in_sizes, int n_in,
                              void* d_out, int out_size, void* d_ws, size_t ws_size,
                              hipStream_t stream) {
  const float* x    = (const float*)d_in[0];
  const float* Wih0 = (const float*)d_in[1];
  const float* Whh0 = (const float*)d_in[2];
  const float* bih0 = (const float*)d_in[3];
  const float* bhh0 = (const float*)d_in[4];
  const float* Wih1 = (const float*)d_in[5];
  const float* Whh1 = (const float*)d_in[6];
  const float* bih1 = (const float*)d_in[7];
  const float* bhh1 = (const float*)d_in[8];
  const float* Wfc  = (const float*)d_in[9];
  const float* bfc  = (const float*)d_in[10];
  float* outp = (float*)d_out;
  _Float16* xp0 = (_Float16*)d_ws;               // B*T*H f16 = 32 MiB scratch

  k_xproj<<<1024, 256, 0, stream>>>(x, Wih0, bih0, bhh0, xp0);
  k_rnn<<<64, 832, 0, stream>>>(xp0, Whh0, Wih1, Whh1, bih1, bhh1, Wfc, bfc, outp);
}